// Round 1
// baseline (249.221 us; speedup 1.0000x reference)
//
#include <hip/hip_runtime.h>
#include <stdint.h>

#define IH 4096
#define IW 4096
#define OH 4090
#define OW 4090

typedef float v2f __attribute__((ext_vector_type(2)));

// Direct (LDS-free) 7x7 valid conv.
// Thread: 4 cols x 8 rows of output (acc[8][4]).
// Wave: 64 lanes x 4 cols = 256 contiguous cols.
// Block: 4 waves = 4 y-bands of 8 rows -> 256x32 output tile.
// Grid: 16 x 128 = 2048 blocks (8/CU, 4 resident at launch_bounds(256,4)).
//
// R6 theory: previous LDS version was latency-bound (VALUBusy 22%, HBM 18%,
// occupancy 20%) -- per-step __syncthreads drained vmcnt(0) including the
// nontemporal stores, and 48KB LDS capped residency at 3 blocks/CU.
// Input (67MB) is L3-resident; horizontal overlap (3 float4/row, 16B shift)
// is intra-wave -> L1 hits; vertical reuse (7x) lives in registers via a
// rolling 3-row buffer (depth-2 prefetch hides ~200cy L2 latency under
// ~224cy of FMAs per row). No barriers anywhere.
__global__ __launch_bounds__(256, 4) void conv7x7_direct(
    const float* __restrict__ x,
    const float* __restrict__ w,
    const float* __restrict__ bias,
    float* __restrict__ out)
{
    const int tid  = threadIdx.x;
    const int tx   = tid & 63;
    const int band = tid >> 6;

    const int x0  = blockIdx.x * 256 + 4 * tx;      // 0..4092, 16B aligned
    const int oy0 = blockIdx.y * 32 + band * 8;     // 0..4088

    // Wave-uniform weights -> SGPRs (s_load).
    float wt[49];
#pragma unroll
    for (int k = 0; k < 49; ++k) wt[k] = w[k];
    const float b = bias[0];

    // x-chunk bases; clamp keeps all 16B loads in-bounds. Clamped lanes only
    // produce garbage in rb slots that feed unstored (>= OW) outputs.
    const int c1 = (x0 + 4 <= IW - 4) ? x0 + 4 : IW - 4;
    const int c2 = (x0 + 8 <= IW - 4) ? x0 + 8 : IW - 4;

    float acc[8][4];
#pragma unroll
    for (int r = 0; r < 8; ++r)
#pragma unroll
        for (int c = 0; c < 4; ++c) acc[r][c] = b;

    // 3-row rotating register buffer, all statically indexed (full unroll).
    float buf[3][12];

#define LOADROW(dst, IR) do {                                              \
        int iy_ = oy0 + (IR);                                              \
        iy_ = iy_ < IH ? iy_ : IH - 1;            /* bottom clamp */       \
        const float* rp_ = x + ((size_t)iy_ << 12);                        \
        const float4 a_ = *(const float4*)(rp_ + x0);                      \
        const float4 b_ = *(const float4*)(rp_ + c1);                      \
        const float4 q_ = *(const float4*)(rp_ + c2);                      \
        dst[0] = a_.x; dst[1] = a_.y; dst[2]  = a_.z; dst[3]  = a_.w;      \
        dst[4] = b_.x; dst[5] = b_.y; dst[6]  = b_.z; dst[7]  = b_.w;      \
        dst[8] = q_.x; dst[9] = q_.y; dst[10] = q_.z; dst[11] = q_.w;      \
    } while (0)

    // Prologue: depth-2 prefetch.
    LOADROW(buf[0], 0);
    LOADROW(buf[1], 1);

#pragma unroll
    for (int ir = 0; ir < 14; ++ir) {
        if (ir + 2 < 14) LOADROW(buf[(ir + 2) % 3], ir + 2);

        const float* rb = buf[ir % 3];

#pragma unroll
        for (int ky = 0; ky < 7; ++ky) {
            const int ry = ir - ky;                 // compile-time folded
            if (ry >= 0 && ry < 8) {
#pragma unroll
                for (int kx = 0; kx < 7; ++kx) {
                    const float ww = wt[ky * 7 + kx];   // SGPR operand
#pragma unroll
                    for (int c = 0; c < 4; ++c)
                        acc[ry][c] += ww * rb[kx + c];  // v_fmac v,s,v
                }
            }
        }
    }
#undef LOADROW

    // Epilogue: out rows are 4090 floats -> (oy*4090 + x0) % 4 in {0,2},
    // so 8B-aligned nontemporal float2 stores. No barrier ever drains these.
#pragma unroll
    for (int ry = 0; ry < 8; ++ry) {
        const int oy = oy0 + ry;
        if (oy < OH) {
            float* orow = out + (size_t)oy * OW + x0;
            if (x0 + 3 < OW) {
                v2f v0 = { acc[ry][0], acc[ry][1] };
                v2f v1 = { acc[ry][2], acc[ry][3] };
                __builtin_nontemporal_store(v0, (v2f*)orow);
                __builtin_nontemporal_store(v1, (v2f*)(orow + 2));
            } else {
#pragma unroll
                for (int c = 0; c < 4; ++c)
                    if (x0 + c < OW) orow[c] = acc[ry][c];
            }
        }
    }
}

extern "C" void kernel_launch(void* const* d_in, const int* in_sizes, int n_in,
                              void* d_out, int out_size, void* d_ws, size_t ws_size,
                              hipStream_t stream) {
    const float* x    = (const float*)d_in[0];
    const float* w    = (const float*)d_in[1];
    const float* bias = (const float*)d_in[2];
    float* out        = (float*)d_out;

    // 16 x-tiles (256 cols) x 128 y-tiles (32 rows) = 2048 blocks.
    dim3 grid((OW + 255) / 256, (OH + 31) / 32);
    conv7x7_direct<<<grid, dim3(256), 0, stream>>>(x, w, bias, out);
}

// Round 3
// 227.186 us; speedup vs baseline: 1.0970x; 1.0970x over previous
//
#include <hip/hip_runtime.h>
#include <stdint.h>

#define IH 4096
#define IW 4096
#define OH 4090
#define OW 4090

#define TW 256            // output cols per block
#define TH 8              // output rows per step (4 waves x 2 rows)
#define STEPS 8           // steps per block -> 64 output rows
#define RING 22           // LDS ring rows = (TH+6 compute) + (TH prefetch)
#define LW 272            // floats per LDS row (68 float4; rows contiguous)
#define YB (TH * STEPS)   // 64

typedef float v2f __attribute__((ext_vector_type(2)));
typedef __attribute__((address_space(1))) void gas_void;
typedef __attribute__((address_space(3))) void las_void;

// R6 post-mortem: LDS-free direct conv amplified FETCH 3.5x / WRITE 3.9x
// (L2 thrash evicts partially-combined 64B output lines). LDS staging is
// load-bearing for traffic cleanliness.
// R0's real stalls: (a) 48KB LDS -> 3/4 blocks resident -> tail round at 1/3
// parallelism; (b) __syncthreads drains vmcnt(0) incl. output stores per step.
// Fix: 23.9KB rolling row-ring (stage only the 8 NEW rows per step; step-s
// write-set {base+14..base+21} mod 22 == step-(s-1)'s retired read rows,
// separated by the end-of-step barrier; current read-set {base..base+13} is
// disjoint) + counted s_waitcnt vmcnt(2) + raw s_barrier (T4: output stores
// stay in flight across the barrier, never drained in the main loop).
// R7 hardening (container failed, no counters): sched_barrier(0) after every
// inline wait/barrier (rule #18), prologue drain via __syncthreads().

__device__ __forceinline__ void stage_row(const float* __restrict__ x,
                                          int iy, int slot, int tile_x0,
                                          float* smem, int tx)
{
    iy = iy < IH ? iy : IH - 1;                       // bottom clamp
    const float* gr = x + ((size_t)iy << 12);
    int c0 = tile_x0 + 4 * tx;
    c0 = c0 <= IW - 4 ? c0 : IW - 4;                  // x clamp, keeps 16B in-bounds
    float* lp = smem + slot * LW;                     // wave-uniform LDS base
    __builtin_amdgcn_global_load_lds((gas_void*)(gr + c0), (las_void*)lp, 16, 0, 0);
    // 68 float4 per row: lanes 0..63 cover c4 0..63, lanes 0..3 cover c4 64..67.
    int c1 = tile_x0 + 256 + 4 * tx;
    c1 = c1 <= IW - 4 ? c1 : IW - 4;
    if (tx < 4)                                       // lanes 0..3 always active -> instr always issued
        __builtin_amdgcn_global_load_lds((gas_void*)(gr + c1), (las_void*)(lp + 256), 16, 0, 0);
}

__global__ __launch_bounds__(256, 4) void conv7x7_ring(
    const float* __restrict__ x,
    const float* __restrict__ w,
    const float* __restrict__ bias,
    float* __restrict__ out)
{
    __shared__ float smem[RING * LW];                 // 23,936 B -> 4 blocks/CU resident

    const int tid = threadIdx.x;
    const int tx  = tid & 63;
    const int wv  = tid >> 6;
    const int tile_x0 = blockIdx.x * TW;
    const int y0 = blockIdx.y * YB;

    // Wave-uniform weights -> SGPRs.
    float wt[49];
#pragma unroll
    for (int k = 0; k < 49; ++k) wt[k] = w[k];
    const float b = bias[0];

    // Prologue: stage rows 0..13 into slots 0..13 (w0:{0,4,8,12} w1:{1,5,9,13}
    // w2:{2,6,10} w3:{3,7,11}).
#pragma unroll
    for (int rr = 0; rr < 4; ++rr) {
        const int r = wv + 4 * rr;
        if (r < 14)
            stage_row(x, y0 + r, r, tile_x0, smem, tx);
    }
    __syncthreads();                                  // compiler-modeled full drain (safe)

    const int lx0 = 4 * tx;
    int base_slot = 0;

#pragma unroll 1
    for (int s = 0; s < STEPS; ++s) {
        // Stage next step's 8 NEW rows (2 per wave) while computing this step.
        if (s + 1 < STEPS) {
#pragma unroll
            for (int j2 = 0; j2 < 2; ++j2) {
                const int j = 2 * wv + j2;
                int sl = base_slot + 14 + j;          // <= 41
                if (sl >= RING) sl -= RING;
                stage_row(x, y0 + TH * s + 14 + j, sl, tile_x0, smem, tx);
            }
        }

        float acc[2][4];
#pragma unroll
        for (int r = 0; r < 2; ++r)
#pragma unroll
            for (int c = 0; c < 4; ++c) acc[r][c] = b;

        const int slot0 = base_slot + 2 * wv;         // <= 26
#pragma unroll
        for (int ir = 0; ir < 8; ++ir) {              // 8 input rows per 2-row band
            int sl = slot0 + ir;                      // <= 33 -> one wrap max
            if (sl >= RING) sl -= RING;
            const float* srow = smem + sl * LW + lx0;
            const float4 q0 = *(const float4*)(srow);       // b128, 16B lane stride
            const float4 q1 = *(const float4*)(srow + 4);
            const float4 q2 = *(const float4*)(srow + 8);
            float rb[12];
            rb[0]=q0.x; rb[1]=q0.y; rb[2]=q0.z;  rb[3]=q0.w;
            rb[4]=q1.x; rb[5]=q1.y; rb[6]=q1.z;  rb[7]=q1.w;
            rb[8]=q2.x; rb[9]=q2.y; rb[10]=q2.z; rb[11]=q2.w;

#pragma unroll
            for (int ky = 0; ky < 7; ++ky) {
                const int ry = ir - ky;               // compile-time folded
                if (ry >= 0 && ry < 2) {
#pragma unroll
                    for (int kx = 0; kx < 7; ++kx) {
                        const float ww = wt[ky * 7 + kx];   // SGPR operand
#pragma unroll
                        for (int c = 0; c < 4; ++c)
                            acc[ry][c] += ww * rb[kx + c];  // v_fmac v,s,v
                    }
                }
            }
        }

        // Stores issued AFTER this step's stage loads -> they are the newest
        // vmem ops; vmcnt(2) below keeps them in flight across the barrier.
        const int ox0 = tile_x0 + lx0;
#pragma unroll
        for (int ry = 0; ry < 2; ++ry) {
            const int oy = y0 + TH * s + 2 * wv + ry;
            if (oy < OH) {                            // wave-uniform
                float* orow = out + (size_t)oy * OW + ox0;
                if (ox0 + 3 < OW) {
                    v2f v0 = { acc[ry][0], acc[ry][1] };
                    v2f v1 = { acc[ry][2], acc[ry][3] };
                    __builtin_nontemporal_store(v0, (v2f*)orow);
                    __builtin_nontemporal_store(v1, (v2f*)(orow + 2));
                } else {
#pragma unroll
                    for (int c = 0; c < 4; ++c)
                        if (ox0 + c < OW) orow[c] = acc[ry][c];
                }
            }
        }

        if (s + 1 < STEPS) {
            // Drain this step's 4 stage loads (oldest); keep newest stores in
            // flight. vmcnt(2) stays correct whether or not the compiler
            // merges the two 8B nt-stores per row.
            asm volatile("s_waitcnt vmcnt(2)" ::: "memory");
            __builtin_amdgcn_sched_barrier(0);
            __builtin_amdgcn_s_barrier();
            __builtin_amdgcn_sched_barrier(0);
            asm volatile("" ::: "memory");            // no ds_read slip above barrier
        }
        base_slot += TH;
        if (base_slot >= RING) base_slot -= RING;
    }
}

extern "C" void kernel_launch(void* const* d_in, const int* in_sizes, int n_in,
                              void* d_out, int out_size, void* d_ws, size_t ws_size,
                              hipStream_t stream) {
    const float* x    = (const float*)d_in[0];
    const float* w    = (const float*)d_in[1];
    const float* bias = (const float*)d_in[2];
    float* out        = (float*)d_out;

    // 16 x-tiles x 64 y-tiles = 1024 blocks = 4/CU dispatched; 23.9KB LDS ->
    // all 4 resident (16 waves/CU) -> single scheduling round, no tail.
    dim3 grid((OW + TW - 1) / TW, (OH + YB - 1) / YB);
    conv7x7_ring<<<grid, dim3(256), 0, stream>>>(x, w, bias, out);
}

// Round 6
// 137.670 us; speedup vs baseline: 1.8103x; 1.6502x over previous
//
#include <hip/hip_runtime.h>
#include <stdint.h>

#define IH 4096
#define IW 4096
#define OH 4090
#define OW 4090

#define TW 256            // output cols per block
#define TH 8              // output rows per step (4 waves x 2 rows)
#define STEPS 8           // steps per block -> 64 output rows
#define RING 22           // LDS ring rows = 14 (compute window) + 8 (prefetch)
#define LW 272            // floats per LDS row
#define YB (TH * STEPS)   // 64

typedef float v2f __attribute__((ext_vector_type(2)));
typedef __attribute__((address_space(1))) void gas_void;
typedef __attribute__((address_space(3))) void las_void;

// R3 (measured): nt half-line stores in flight across counted-vmcnt barriers
// never write-combine -> WRITE 296MB (4.4x RMW), FETCH 137MB, 141us.
// R4 (measured): shift-clamped tiles + temporal stores FAILED numerics
// (absmax 2.5e-2): last x-tile's 16B second chunk at tx=1 wants x[4094..4097],
// address-clamp to 4092 SHIFTS data -> LDS cols 260..261 (consumed by stored
// edge outputs) hold x[4092..4093]. R0/R3 masked this via store guards.
// R5 fixes:
//  (a) second chunk staged via global_load_lds size=4 (16 lanes x 1 float,
//      per-float clamp min(c, IW-1)): LDS col <-> x col mapping exact for all
//      consumed cols (max consumed col 261; 262..271 clamp-garbage, unread).
//      Still 2 vmem instrs per stage_row -> vmcnt ledger unchanged.
//  (b) sched_barrier(0) after the staging block: pins the 4 loads ahead of
//      the 4 stores in issue order -> vmcnt(4) provably drains exactly the
//      stage loads; temporal stores float across the barrier and combine in
//      L2 (write-allocate), immune to interleaving.
// Ring invariants: step-s write-set {base+14..+21} mod 22 == step-(s-1)'s
// retired read rows (barrier-separated); read-set {base..base+13} disjoint.

__device__ __forceinline__ void stage_row(const float* __restrict__ x,
                                          int iy, int slot, int tile_x0,
                                          float* smem, int tx)
{
    iy = iy < IH ? iy : IH - 1;                       // bottom clamp (never feeds stored outputs)
    const float* gr = x + ((size_t)iy << 12);
    // Chunk 1: 64 lanes x 16B -> LDS cols 0..255 <- x[tile_x0 .. tile_x0+255].
    // tile_x0 <= 3834 so c0 <= 4086 <= IW-4: always in-bounds, no shift.
    const int c0 = tile_x0 + 4 * tx;
    float* lp = smem + slot * LW;                     // wave-uniform LDS base
    __builtin_amdgcn_global_load_lds((gas_void*)(gr + c0), (las_void*)lp, 16, 0, 0);
    // Chunk 2: 16 lanes x 4B -> LDS cols 256..271 <- x[tile_x0+256+tx], each
    // float clamped independently (exact mapping for every consumed column).
    int c1 = tile_x0 + 256 + tx;
    c1 = c1 <= IW - 1 ? c1 : IW - 1;
    if (tx < 16)                                      // lanes 0..15 always active -> always issued
        __builtin_amdgcn_global_load_lds((gas_void*)(gr + c1), (las_void*)(lp + 256), 4, 0, 0);
}

__global__ __launch_bounds__(256, 4) void conv7x7_ring(
    const float* __restrict__ x,
    const float* __restrict__ w,
    const float* __restrict__ bias,
    float* __restrict__ out)
{
    __shared__ float smem[RING * LW];                 // 23,936 B -> 4 blocks/CU resident

    const int tid = threadIdx.x;
    const int tx  = tid & 63;
    const int wv  = tid >> 6;

    // Shift-clamped tile origins: edge tiles recompute the overlap (identical
    // values, benign double-store) -> guard-free epilogue, uniform vmem counts.
    int tile_x0 = blockIdx.x * TW;
    if (tile_x0 > OW - TW) tile_x0 = OW - TW;         // 3834 (even -> 8B store align)
    int y0 = blockIdx.y * YB;
    if (y0 > OH - YB) y0 = OH - YB;                   // 4026 (max staged row = 4095, no clamp garbage consumed)

    // Wave-uniform weights -> SGPRs.
    float wt[49];
#pragma unroll
    for (int k = 0; k < 49; ++k) wt[k] = w[k];
    const float b = bias[0];

    // Prologue: stage rows 0..13 into slots 0..13.
#pragma unroll
    for (int rr = 0; rr < 4; ++rr) {
        const int r = wv + 4 * rr;
        if (r < 14)
            stage_row(x, y0 + r, r, tile_x0, smem, tx);
    }
    __syncthreads();                                  // full drain (prologue only)

    const int lx0 = 4 * tx;
    int base_slot = 0;

#pragma unroll 1
    for (int s = 0; s < STEPS; ++s) {
        // Stage next step's 8 NEW rows (2 per wave) while computing this step.
        if (s + 1 < STEPS) {
#pragma unroll
            for (int j2 = 0; j2 < 2; ++j2) {
                const int j = 2 * wv + j2;
                int sl = base_slot + 14 + j;          // <= 41
                if (sl >= RING) sl -= RING;
                stage_row(x, y0 + TH * s + 14 + j, sl, tile_x0, smem, tx);
            }
            // Pin: all 4 stage loads issue before anything below (so the
            // vmcnt(4) ledger "oldest 4 = loads" is guaranteed).
            __builtin_amdgcn_sched_barrier(0);
        }

        float acc[2][4];
#pragma unroll
        for (int r = 0; r < 2; ++r)
#pragma unroll
            for (int c = 0; c < 4; ++c) acc[r][c] = b;

        const int slot0 = base_slot + 2 * wv;         // <= 26
#pragma unroll
        for (int ir = 0; ir < 8; ++ir) {              // 8 input rows per 2-row band
            int sl = slot0 + ir;                      // <= 33 -> one wrap max
            if (sl >= RING) sl -= RING;
            const float* srow = smem + sl * LW + lx0;
            const float4 q0 = *(const float4*)(srow);       // b128, 16B lane stride
            const float4 q1 = *(const float4*)(srow + 4);
            const float4 q2 = *(const float4*)(srow + 8);   // rb[10],rb[11] unused
            float rb[12];
            rb[0]=q0.x; rb[1]=q0.y; rb[2]=q0.z;  rb[3]=q0.w;
            rb[4]=q1.x; rb[5]=q1.y; rb[6]=q1.z;  rb[7]=q1.w;
            rb[8]=q2.x; rb[9]=q2.y; rb[10]=q2.z; rb[11]=q2.w;

#pragma unroll
            for (int ky = 0; ky < 7; ++ky) {
                const int ry = ir - ky;               // compile-time folded
                if (ry >= 0 && ry < 2) {
#pragma unroll
                    for (int kx = 0; kx < 7; ++kx) {
                        const float ww = wt[ky * 7 + kx];   // SGPR operand
#pragma unroll
                        for (int c = 0; c < 4; ++c)
                            acc[ry][c] += ww * rb[kx + c];  // v_fmac v,s,v
                    }
                }
            }
        }

        // Guard-free epilogue: temporal 8B stores (L2 write-allocate merges
        // half-lines + tile-boundary partials in cache). Exactly 4 store
        // instructions per wave per step, all issued after the 4 stage loads.
        const int ox0 = tile_x0 + lx0;
#pragma unroll
        for (int ry = 0; ry < 2; ++ry) {
            const int oy = y0 + TH * s + 2 * wv + ry;
            float* orow = out + (size_t)oy * OW + ox0;
            *(v2f*)orow       = (v2f){ acc[ry][0], acc[ry][1] };
            *(v2f*)(orow + 2) = (v2f){ acc[ry][2], acc[ry][3] };
        }

        if (s + 1 < STEPS) {
            // Outstanding (oldest->newest): 4 stage loads, then 4 stores.
            // vmcnt(4) drains exactly the loads; stores float freely.
            asm volatile("s_waitcnt vmcnt(4)" ::: "memory");
            __builtin_amdgcn_sched_barrier(0);
            __builtin_amdgcn_s_barrier();
            __builtin_amdgcn_sched_barrier(0);
            asm volatile("" ::: "memory");            // no ds_read slip above barrier
        }
        base_slot += TH;
        if (base_slot >= RING) base_slot -= RING;
    }
}

extern "C" void kernel_launch(void* const* d_in, const int* in_sizes, int n_in,
                              void* d_out, int out_size, void* d_ws, size_t ws_size,
                              hipStream_t stream) {
    const float* x    = (const float*)d_in[0];
    const float* w    = (const float*)d_in[1];
    const float* bias = (const float*)d_in[2];
    float* out        = (float*)d_out;

    // 16 x-tiles x 64 y-tiles = 1024 blocks = 4/CU dispatched; 23.9KB LDS ->
    // all 4 resident (16 waves/CU) -> single scheduling round, no tail.
    dim3 grid((OW + TW - 1) / TW, (OH + YB - 1) / YB);
    conv7x7_ring<<<grid, dim3(256), 0, stream>>>(x, w, bias, out);
}

// Round 7
// 132.773 us; speedup vs baseline: 1.8770x; 1.0369x over previous
//
#include <hip/hip_runtime.h>
#include <stdint.h>

#define IH 4096
#define IW 4096
#define OH 4090
#define OW 4090

#define TW 256            // output cols per block
#define TH 16             // output rows per step (4 waves x 4 rows)
#define STEPS 8           // steps per block -> 128 output rows
#define RING 38           // LDS ring rows = 22 (compute window) + 16 (prefetch)
#define LW 272            // floats per LDS row
#define YB (TH * STEPS)   // 128

typedef float v2f __attribute__((ext_vector_type(2)));
typedef __attribute__((address_space(1))) void gas_void;
typedef __attribute__((address_space(3))) void las_void;

// R6 (measured, 55.4us): traffic clean (FETCH 40MB, WRITE 67MB); bottleneck is
// the LDS read pipe: 13.04M SQ_LDS_BANK_CONFLICT cycles (=21us/CU) + ~15us/CU
// base issue over 786K ds_read_b128. Cost per b128 (~12-17 extra cyc) is
// intrinsic to the 16B-lane-stride pattern (same ratio in R0) -> lever is
// FEWER READS PER OUTPUT, not swizzle (lanes read the same row; no row-axis
// conflict exists). Bytes/output = 3*16*(r+6)/(4r): r=2 -> 48, r=4 -> 30.
// R7: r=4 rows/wave (TH=16, RING=38, 41.3KB LDS), STEPS=8 -> 512 blocks =
// 2/CU dispatched with 3/CU residency -> all co-resident, no tail.
// Everything else (exact-granularity staging, temporal stores, counted
// vmcnt ledger, shift-clamped tiles) is R6's verified structure.
// Ledger: 8 stage loads then 8 stores per wave-step -> vmcnt(8) drains
// exactly the loads; stores float across the barrier and combine in L2.

__device__ __forceinline__ void stage_row(const float* __restrict__ x,
                                          int iy, int slot, int tile_x0,
                                          float* smem, int tx)
{
    iy = iy < IH ? iy : IH - 1;                       // safety clamp (never consumed)
    const float* gr = x + ((size_t)iy << 12);
    // Chunk 1: 64 lanes x 16B -> LDS cols 0..255 <- x[tile_x0 .. tile_x0+255].
    // tile_x0 <= 3834 so c0 <= 4086 <= IW-4: always in-bounds, exact mapping.
    const int c0 = tile_x0 + 4 * tx;
    float* lp = smem + slot * LW;                     // wave-uniform LDS base
    __builtin_amdgcn_global_load_lds((gas_void*)(gr + c0), (las_void*)lp, 16, 0, 0);
    // Chunk 2: 16 lanes x 4B -> LDS cols 256..271, each float clamped
    // independently (exact mapping for every consumed col; max consumed 261).
    int c1 = tile_x0 + 256 + tx;
    c1 = c1 <= IW - 1 ? c1 : IW - 1;
    if (tx < 16)                                      // lanes 0..15 always active -> always issued
        __builtin_amdgcn_global_load_lds((gas_void*)(gr + c1), (las_void*)(lp + 256), 4, 0, 0);
}

__global__ __launch_bounds__(256, 3) void conv7x7_ring(
    const float* __restrict__ x,
    const float* __restrict__ w,
    const float* __restrict__ bias,
    float* __restrict__ out)
{
    __shared__ float smem[RING * LW];                 // 41,344 B -> 3 blocks/CU residency

    const int tid = threadIdx.x;
    const int tx  = tid & 63;
    const int wv  = tid >> 6;

    // Shift-clamped tile origins: edge tiles recompute the overlap (identical
    // values, benign double-store) -> guard-free epilogue, uniform vmem counts.
    int tile_x0 = blockIdx.x * TW;
    if (tile_x0 > OW - TW) tile_x0 = OW - TW;         // 3834 (even -> 8B store align)
    int y0 = blockIdx.y * YB;
    if (y0 > OH - YB) y0 = OH - YB;                   // 3962; max staged row = y0+133 = 4095, exact

    // Wave-uniform weights -> SGPRs.
    float wt[49];
#pragma unroll
    for (int k = 0; k < 49; ++k) wt[k] = w[k];
    const float b = bias[0];

    // Prologue: stage rows 0..21 into slots 0..21 (waves 0,1: 6 rows; 2,3: 5).
#pragma unroll
    for (int rr = 0; rr < 6; ++rr) {
        const int r = wv + 4 * rr;
        if (r < 22)
            stage_row(x, y0 + r, r, tile_x0, smem, tx);
    }
    __syncthreads();                                  // full drain (prologue only)

    const int lx0 = 4 * tx;
    int base_slot = 0;

#pragma unroll 1
    for (int s = 0; s < STEPS; ++s) {
        // Stage next step's 16 NEW rows (4 per wave) while computing this one.
        // Write slots base+22..base+37 mod 38 == step-(s-1)'s retired read
        // rows (barrier-separated); read set base..base+21 disjoint.
        if (s + 1 < STEPS) {
#pragma unroll
            for (int j2 = 0; j2 < 4; ++j2) {
                const int j = 4 * wv + j2;
                int sl = base_slot + 22 + j;          // <= 73
                if (sl >= RING) sl -= RING;
                stage_row(x, y0 + TH * s + 22 + j, sl, tile_x0, smem, tx);
            }
            // Pin: all 8 stage loads issue before anything below (vmcnt(8)
            // ledger "oldest 8 = loads" guaranteed).
            __builtin_amdgcn_sched_barrier(0);
        }

        float acc[4][4];
#pragma unroll
        for (int r = 0; r < 4; ++r)
#pragma unroll
            for (int c = 0; c < 4; ++c) acc[r][c] = b;

#pragma unroll
        for (int ir = 0; ir < 10; ++ir) {             // 10 input rows per 4-row band
            int sl = base_slot + 4 * wv + ir;         // <= 36+12+9 = 57 -> one wrap max
            if (sl >= RING) sl -= RING;
            const float* srow = smem + sl * LW + lx0;
            const float4 q0 = *(const float4*)(srow);       // b128, 16B lane stride
            const float4 q1 = *(const float4*)(srow + 4);
            const float4 q2 = *(const float4*)(srow + 8);   // floats 8,9 used
            float rb[12];
            rb[0]=q0.x; rb[1]=q0.y; rb[2]=q0.z;  rb[3]=q0.w;
            rb[4]=q1.x; rb[5]=q1.y; rb[6]=q1.z;  rb[7]=q1.w;
            rb[8]=q2.x; rb[9]=q2.y; rb[10]=q2.z; rb[11]=q2.w;

#pragma unroll
            for (int ky = 0; ky < 7; ++ky) {
                const int ry = ir - ky;               // compile-time folded
                if (ry >= 0 && ry < 4) {
#pragma unroll
                    for (int kx = 0; kx < 7; ++kx) {
                        const float ww = wt[ky * 7 + kx];   // SGPR operand
#pragma unroll
                        for (int c = 0; c < 4; ++c)
                            acc[ry][c] += ww * rb[kx + c];  // v_fmac v,s,v
                    }
                }
            }
        }

        // Guard-free epilogue: temporal 8B stores (L2 write-allocate merges
        // half-lines + tile-boundary partials). Exactly 8 stores per wave per
        // step, all issued after the 8 stage loads.
        const int ox0 = tile_x0 + lx0;
#pragma unroll
        for (int ry = 0; ry < 4; ++ry) {
            const int oy = y0 + TH * s + 4 * wv + ry;
            float* orow = out + (size_t)oy * OW + ox0;
            *(v2f*)orow       = (v2f){ acc[ry][0], acc[ry][1] };
            *(v2f*)(orow + 2) = (v2f){ acc[ry][2], acc[ry][3] };
        }

        if (s + 1 < STEPS) {
            // Outstanding (oldest->newest): 8 stage loads, then 8 stores.
            // vmcnt(8) drains exactly the loads; stores float freely.
            asm volatile("s_waitcnt vmcnt(8)" ::: "memory");
            __builtin_amdgcn_sched_barrier(0);
            __builtin_amdgcn_s_barrier();
            __builtin_amdgcn_sched_barrier(0);
            asm volatile("" ::: "memory");            // no ds_read slip above barrier
        }
        base_slot += TH;
        if (base_slot >= RING) base_slot -= RING;
    }
}

extern "C" void kernel_launch(void* const* d_in, const int* in_sizes, int n_in,
                              void* d_out, int out_size, void* d_ws, size_t ws_size,
                              hipStream_t stream) {
    const float* x    = (const float*)d_in[0];
    const float* w    = (const float*)d_in[1];
    const float* bias = (const float*)d_in[2];
    float* out        = (float*)d_out;

    // 16 x-tiles x 32 y-tiles = 512 blocks = 2/CU dispatched, 3/CU residency
    // allowed (41.3KB LDS) -> all blocks co-resident, single round, no tail.
    dim3 grid((OW + TW - 1) / TW, (4096) / YB);
    conv7x7_ring<<<grid, dim3(256), 0, stream>>>(x, w, bias, out);
}

// Round 8
// 132.080 us; speedup vs baseline: 1.8869x; 1.0052x over previous
//
#include <hip/hip_runtime.h>
#include <stdint.h>

#define IH 4096
#define IW 4096
#define OH 4090
#define OW 4090

#define TW 256            // output cols per block
#define NW 8              // waves per block (512 threads)
#define TH 32             // output rows per step (8 waves x 4 rows)
#define STEPS 4           // steps per block -> 128 output rows
#define WIN 38            // compute window rows (TH+6)
#define RING 70           // WIN + TH prefetch
#define LW 272            // floats per LDS row
#define YB (TH * STEPS)   // 128

typedef float v2f __attribute__((ext_vector_type(2)));
typedef __attribute__((address_space(1))) void gas_void;
typedef __attribute__((address_space(3))) void las_void;

// R7 (measured, 47.6us): conflicts scaled exactly with read count (13.0->8.3M,
// predicted 8.1M) -> per-b128 cost intrinsic, lever = read count. But dur
// missed prediction: OccupancyPercent 28->16% (512 blocks = 2/CU = 2 waves/
// SIMD) -- nothing saturated (VALU 35%, LDS ~35%, HBM 28%): LATENCY-bound on
// too-few waves.
// R8: 8-wave (512-thread) blocks. Per-wave code identical (4 rows x 256 cols,
// 30B LDS-read/output); TH=32/step, RING=70 rows (38 window + 32 prefetch) =
// 76.2KB -> exactly 2 blocks/CU = 16 waves/CU = 4 waves/SIMD (2x R7's hiding
// depth). Grid 16x32=512 blocks = exactly 2/CU, single round, no tail.
// Barriers/block 7 -> 3. Ledger per wave unchanged: 8 stage loads then 8
// temporal stores -> vmcnt(8) drains exactly the loads, stores float and
// combine in L2. Ring: reads base..base+37, writes base+38..base+69 mod 70,
// disjoint; max staged row = 3962+64+38+31 = 4095 exact.

__device__ __forceinline__ void stage_row(const float* __restrict__ x,
                                          int iy, int slot, int tile_x0,
                                          float* smem, int tx)
{
    iy = iy < IH ? iy : IH - 1;                       // safety clamp (never consumed)
    const float* gr = x + ((size_t)iy << 12);
    // Chunk 1: 64 lanes x 16B -> LDS cols 0..255 <- x[tile_x0..tile_x0+255].
    // tile_x0 <= 3834 so c0 <= 4086 <= IW-4: always in-bounds, exact mapping.
    const int c0 = tile_x0 + 4 * tx;
    float* lp = smem + slot * LW;                     // wave-uniform LDS base
    __builtin_amdgcn_global_load_lds((gas_void*)(gr + c0), (las_void*)lp, 16, 0, 0);
    // Chunk 2: 16 lanes x 4B -> LDS cols 256..271, per-float clamp (exact
    // mapping for every consumed col; max consumed 261).
    int c1 = tile_x0 + 256 + tx;
    c1 = c1 <= IW - 1 ? c1 : IW - 1;
    if (tx < 16)                                      // lanes 0..15 always active -> always issued
        __builtin_amdgcn_global_load_lds((gas_void*)(gr + c1), (las_void*)(lp + 256), 4, 0, 0);
}

__global__ __launch_bounds__(512, 4) void conv7x7_ring(
    const float* __restrict__ x,
    const float* __restrict__ w,
    const float* __restrict__ bias,
    float* __restrict__ out)
{
    __shared__ float smem[RING * LW];                 // 76,160 B -> 2 blocks/CU resident

    const int tid = threadIdx.x;
    const int tx  = tid & 63;
    const int wv  = tid >> 6;                         // 0..7

    // Shift-clamped tile origins: edge tiles recompute the overlap (identical
    // values, benign double-store) -> guard-free epilogue, uniform vmem counts.
    int tile_x0 = blockIdx.x * TW;
    if (tile_x0 > OW - TW) tile_x0 = OW - TW;         // 3834 (even -> 8B store align)
    int y0 = blockIdx.y * YB;
    if (y0 > OH - YB) y0 = OH - YB;                   // 3962

    // Wave-uniform weights -> SGPRs.
    float wt[49];
#pragma unroll
    for (int k = 0; k < 49; ++k) wt[k] = w[k];
    const float b = bias[0];

    // Prologue: stage rows 0..37 into slots 0..37 (waves 0..5: 5 rows; 6,7: 4).
#pragma unroll
    for (int rr = 0; rr < 5; ++rr) {
        const int r = wv + NW * rr;
        if (r < WIN)
            stage_row(x, y0 + r, r, tile_x0, smem, tx);
    }
    __syncthreads();                                  // full drain (prologue only)

    const int lx0 = 4 * tx;
    int base_slot = 0;

#pragma unroll 1
    for (int s = 0; s < STEPS; ++s) {
        // Stage next step's 32 NEW rows (4 per wave) while computing this one.
        if (s + 1 < STEPS) {
#pragma unroll
            for (int j2 = 0; j2 < 4; ++j2) {
                const int j = 4 * wv + j2;            // 0..31
                int sl = base_slot + WIN + j;         // <= 69+38+31=138 -> one wrap
                if (sl >= RING) sl -= RING;
                stage_row(x, y0 + TH * s + WIN + j, sl, tile_x0, smem, tx);
            }
            // Pin: all 8 stage loads issue before anything below (vmcnt(8)
            // ledger "oldest 8 = loads" guaranteed).
            __builtin_amdgcn_sched_barrier(0);
        }

        float acc[4][4];
#pragma unroll
        for (int r = 0; r < 4; ++r)
#pragma unroll
            for (int c = 0; c < 4; ++c) acc[r][c] = b;

#pragma unroll
        for (int ir = 0; ir < 10; ++ir) {             // 10 input rows per 4-row band
            int sl = base_slot + 4 * wv + ir;         // <= 69+28+9=106 -> one wrap
            if (sl >= RING) sl -= RING;
            const float* srow = smem + sl * LW + lx0;
            const float4 q0 = *(const float4*)(srow);       // b128, 16B lane stride
            const float4 q1 = *(const float4*)(srow + 4);
            const float4 q2 = *(const float4*)(srow + 8);   // floats 8,9 used
            float rb[12];
            rb[0]=q0.x; rb[1]=q0.y; rb[2]=q0.z;  rb[3]=q0.w;
            rb[4]=q1.x; rb[5]=q1.y; rb[6]=q1.z;  rb[7]=q1.w;
            rb[8]=q2.x; rb[9]=q2.y; rb[10]=q2.z; rb[11]=q2.w;

#pragma unroll
            for (int ky = 0; ky < 7; ++ky) {
                const int ry = ir - ky;               // compile-time folded
                if (ry >= 0 && ry < 4) {
#pragma unroll
                    for (int kx = 0; kx < 7; ++kx) {
                        const float ww = wt[ky * 7 + kx];   // SGPR operand
#pragma unroll
                        for (int c = 0; c < 4; ++c)
                            acc[ry][c] += ww * rb[kx + c];  // v_fmac v,s,v
                    }
                }
            }
        }

        // Guard-free epilogue: temporal 8B stores (L2 write-allocate merges
        // half-lines + tile-boundary partials). Exactly 8 stores per wave per
        // step, all issued after the 8 stage loads.
        const int ox0 = tile_x0 + lx0;
#pragma unroll
        for (int ry = 0; ry < 4; ++ry) {
            const int oy = y0 + TH * s + 4 * wv + ry;
            float* orow = out + (size_t)oy * OW + ox0;
            *(v2f*)orow       = (v2f){ acc[ry][0], acc[ry][1] };
            *(v2f*)(orow + 2) = (v2f){ acc[ry][2], acc[ry][3] };
        }

        if (s + 1 < STEPS) {
            // Outstanding (oldest->newest): 8 stage loads, then 8 stores.
            // vmcnt(8) drains exactly the loads; stores float freely.
            asm volatile("s_waitcnt vmcnt(8)" ::: "memory");
            __builtin_amdgcn_sched_barrier(0);
            __builtin_amdgcn_s_barrier();
            __builtin_amdgcn_sched_barrier(0);
            asm volatile("" ::: "memory");            // no ds_read slip above barrier
        }
        base_slot += TH;
        if (base_slot >= RING) base_slot -= RING;
    }
}

extern "C" void kernel_launch(void* const* d_in, const int* in_sizes, int n_in,
                              void* d_out, int out_size, void* d_ws, size_t ws_size,
                              hipStream_t stream) {
    const float* x    = (const float*)d_in[0];
    const float* w    = (const float*)d_in[1];
    const float* bias = (const float*)d_in[2];
    float* out        = (float*)d_out;

    // 16 x-tiles x 32 y-tiles = 512 blocks (512 thr) = exactly 2/CU resident
    // (76.2KB LDS) = 16 waves/CU = 4 waves/SIMD; single round, no tail.
    dim3 grid((OW + TW - 1) / TW, 4096 / YB);
    conv7x7_ring<<<grid, dim3(512), 0, stream>>>(x, w, bias, out);
}